// Round 15
// baseline (572.608 us; speedup 1.0000x reference)
//
#include <hip/hip_runtime.h>

namespace {
typedef unsigned short u16;
typedef __attribute__((ext_vector_type(8))) __bf16 bf16x8;
typedef __attribute__((ext_vector_type(4))) float f32x4;

constexpr long long kB  = 4096;
constexpr long long kOS = kB * 3600;
constexpr size_t kGAs = 4096ull * 1088;   // per-rim gA stride (elems), row = 1088
constexpr int kHnS = 3648;                // hnbf row stride (u16), cols 3600-3647 zeroed

// ---- ws byte offsets ----
constexpr size_t oWkvT  = 0;                               // bf16 [768][512]
constexpr size_t oWqT   = oWkvT  + 768ull*512*2;           // bf16 [6][256][640]
constexpr size_t oWcomT = oWqT   + 6ull*256*640*2;         // bf16 [6][768][640]
constexpr size_t oWoutT = oWcomT + 6ull*768*640*2;         // bf16 [6][640][448]
constexpr size_t oLstmT = oWoutT + 6ull*640*448*2;         // bf16 [6][2560][1024] (rows 2432+ zero)
constexpr size_t oBp    = oLstmT + 6ull*2560*1024*2;       // f32 [6][2560]
constexpr size_t oBkv   = oBp    + 6ull*2560*4;            // f32 [768]
constexpr size_t oMask  = oBkv   + 768*4;                  // f32 [4096][6]
constexpr size_t oArena = oMask  + 4096ull*6*4;
// phase-1 arena
constexpr size_t oGA    = oArena;                          // bf16 [6][4096][1088] (rnn|hs|pad0)
constexpr size_t oKV    = oGA   + 6ull*kGAs*2;             // bf16 [4096][768]
constexpr size_t oXbf   = oKV   + 4096ull*768*2;           // bf16 [4096][512]
constexpr size_t oQlay  = oXbf;                            // bf16 [4096][1536], overlays xbf AFTER kv gemm
// phase-2 overlay (phase-1 arena dead by then)
constexpr size_t oCqv   = oArena;                          // bf16 [4096][4608]
constexpr size_t oCtx   = oCqv  + 4096ull*4608*2;          // bf16 [4096][2400]+64
}

__device__ __forceinline__ u16 f2b(float f) {
  union { float f; unsigned u; } x; x.f = f;
  unsigned r = (x.u + 0x7fffu + ((x.u >> 16) & 1u)) >> 16;
  return (u16)r;
}
__device__ __forceinline__ float b2f(u16 u) {
  union { unsigned u; float f; } x; x.u = ((unsigned)u) << 16;
  return x.f;
}
__device__ __forceinline__ float sigmoidf_(float x) { return 1.f / (1.f + __expf(-x)); }
__device__ __forceinline__ float tanhf_(float x) {
  const float e = __expf(2.f * x);
  return 1.f - 2.f / (e + 1.f);
}

__device__ __forceinline__ void gload16(const void* g, void* l) {
  __builtin_amdgcn_global_load_lds((const __attribute__((address_space(1))) void*)g,
                                   (__attribute__((address_space(3))) void*)l, 16, 0, 0);
}

union FragU4 { uint4 u4; bf16x8 v; };

// ====== unified 128x128 bf16 MFMA GEMM, BK=64, 2-buf stage-early (r7 core, proven) ======
// MODE 0: C=A*B(+bias). MODE 1: final (mask select, 2 outputs).
template<int MODE>
__global__ __launch_bounds__(256, 2) void gemm64(
    const u16* __restrict__ A, int lda, long strideA,
    const u16* __restrict__ Bt, long strideB, int Kpad,
    void* __restrict__ C, int ldc, int strideC,
    const float* __restrict__ bias, int strideBias,
    int N, int nks, int storeBf16, int nx,
    const float* __restrict__ mask, float* __restrict__ h_upd,
    const float* __restrict__ hs_in, float* __restrict__ out_state)
{
  __shared__ __align__(16) u16 lds[2 * 16384];

  const int nwg = gridDim.x;
  const int orig = blockIdx.x;
  int wgid;
  {
    const int q = nwg >> 3, r = nwg & 7;
    const int xcd = orig & 7, bidx = orig >> 3;
    wgid = (xcd < r ? xcd * (q + 1) : r * (q + 1) + (xcd - r) * q) + bidx;
  }
  const int xt = wgid % nx;
  const int t2 = wgid / nx;
  const int mt = t2 & 31;
  const int rim = t2 >> 5;
  const int m0 = mt * 128, n0 = xt * 128;

  A += (size_t)rim * strideA;
  Bt += (size_t)rim * strideB;
  if (bias) bias += (size_t)rim * strideBias;

  const int t = threadIdx.x;
  const int w = t >> 6, lane = t & 63;
  const int lrow = lane & 15, lk = lane >> 4;
  const int wr = w >> 1, wc = w & 1;

  f32x4 acc[4][4] = {};

  const u16* aS[4]; const u16* bS[4]; int cC[4];
#pragma unroll
  for (int i = 0; i < 4; ++i) {
    const int c = t + i * 256;
    const int row = c >> 3, slot = c & 7;
    cC[i] = c;
    aS[i] = A  + (size_t)(m0 + row) * lda  + ((slot ^ (row & 7)) << 3);
    bS[i] = Bt + (size_t)(n0 + row) * Kpad + ((slot ^ (row & 7)) << 3);
  }
  auto stage = [&](u16* dst) {
#pragma unroll
    for (int i = 0; i < 4; ++i) gload16(aS[i], dst + (size_t)cC[i] * 8);
#pragma unroll
    for (int i = 0; i < 4; ++i) gload16(bS[i], dst + 8192 + (size_t)cC[i] * 8);
#pragma unroll
    for (int i = 0; i < 4; ++i) { aS[i] += 64; bS[i] += 64; }
  };

  stage(lds);
  asm volatile("s_waitcnt vmcnt(0)" ::: "memory");
  __builtin_amdgcn_s_barrier();

  for (int s = 0; s < nks; ++s) {
    const bool more = (s + 1 < nks);
    if (more) stage(lds + ((s + 1) & 1) * 16384);
    __builtin_amdgcn_sched_barrier(0);
    const char* Ab = (const char*)(lds + (s & 1) * 16384);
    const char* Bb = Ab + 16384;
#pragma unroll
    for (int ks = 0; ks < 2; ++ks) {
      FragU4 af[4], bf4[4];
#pragma unroll
      for (int mf = 0; mf < 4; ++mf) {
        const int rr = wr * 64 + mf * 16 + lrow;
        af[mf].u4 = *(const uint4*)(Ab + rr * 128 + ((((ks << 2) | lk) ^ (rr & 7)) << 4));
      }
#pragma unroll
      for (int nf = 0; nf < 4; ++nf) {
        const int rr = wc * 64 + nf * 16 + lrow;
        bf4[nf].u4 = *(const uint4*)(Bb + rr * 128 + ((((ks << 2) | lk) ^ (rr & 7)) << 4));
      }
#pragma unroll
      for (int mf = 0; mf < 4; ++mf)
#pragma unroll
        for (int nf = 0; nf < 4; ++nf)
          acc[mf][nf] = __builtin_amdgcn_mfma_f32_16x16x32_bf16(af[mf].v, bf4[nf].v, acc[mf][nf], 0, 0, 0);
    }
    if (more) {
      asm volatile("s_waitcnt vmcnt(0)" ::: "memory");
      __builtin_amdgcn_s_barrier();
    }
  }

  if (MODE == 0) {
    float* Cf = (float*)C + (size_t)rim * strideC;
    u16*   Cu = (u16*)C + (size_t)rim * strideC;
#pragma unroll
    for (int mf = 0; mf < 4; ++mf)
#pragma unroll
      for (int r2 = 0; r2 < 4; ++r2) {
        const int m = m0 + wr * 64 + mf * 16 + 4 * lk + r2;
#pragma unroll
        for (int nf = 0; nf < 4; ++nf) {
          const int col = n0 + wc * 64 + nf * 16 + lrow;
          if (col < N) {
            float v = acc[mf][nf][r2];
            if (bias) v += bias[col];
            const size_t off = (size_t)m * ldc + col;
            if (storeBf16) Cu[off] = f2b(v); else Cf[off] = v;
          }
        }
      }
  } else {
#pragma unroll
    for (int mf = 0; mf < 4; ++mf)
#pragma unroll
      for (int r2 = 0; r2 < 4; ++r2) {
        const int m = m0 + wr * 64 + mf * 16 + 4 * lk + r2;
        const float mk = mask[(size_t)m * 6 + rim];
#pragma unroll
        for (int nf = 0; nf < 4; ++nf) {
          const int col = n0 + wc * 64 + nf * 16 + lrow;
          if (col < 600) {
            const size_t off = (size_t)m * 3600 + rim * 600 + col;
            const float v = (mk != 0.f) ? (acc[mf][nf][r2] + h_upd[off]) : hs_in[off];
            h_upd[off] = v;
            out_state[off] = v;
          }
        }
      }
  }
}

// ====== gates: 256x256 bf16 MFMA + fused LSTM, consumption-aligned 4-phase pipeline ======
// 512 thr = 8 waves (2M x 4N), wave 128x64 (acc 8x4). LDS 2 buf x 64KB.
// Per buf: A quarter-units (8KB each): A(ks,h) @ (ks*2+h)*8192B, rows folded
// {h*64..h*64+63, 128+h*64..}; B k-half units (16KB): B(ks) @ 32768+ks*16384B.
// Unit internal: row' x 64B, slot = lk ^ ((row'>>1)&3) XOR (2 words/bank = free);
// staging strictly lane-linear (dest = unit_base + chunk*16B), involution on the
// per-lane GLOBAL source (both-sides rule).
// Phase p consumes batch s_p, staged 4 phases earlier: s0={A(0,0),B(0)}:3 loads/thr,
// s1={A(0,1)}:1, s2={A(1,0),B(1)}:3, s3={A(1,1)}:1. Waits (counted, never drain
// mid-loop): steady {5,7,5,7}, tail {5,4,1,0}; 3 batches in flight (m201 depth).
// Barrier every phase (cross-wave visibility); WAR separation >= 4 barriers.
__global__ __launch_bounds__(512, 2) void gates256(
    const u16* __restrict__ A, const u16* __restrict__ Bt,
    const float* __restrict__ bp, const float* __restrict__ cs,
    const float* __restrict__ mask,
    float* __restrict__ c_upd, float* __restrict__ h_upd, u16* __restrict__ hnbf)
{
  __shared__ __align__(16) u16 lds[2 * 32768];   // 2 buf x 64KB

  const int orig = blockIdx.x;                   // grid 960: q=120, r=0
  const int wgid = (orig & 7) * 120 + (orig >> 3);
  const int rim = wgid / 160;
  const int rem = wgid % 160;
  const int half = rem / 80;
  const int r2d = rem % 80;
  const int mt = r2d / 5;
  const int xt = half * 5 + r2d % 5;
  const int m0 = mt * 256, n0 = xt * 256;

  const u16* Ar = A + (size_t)rim * kGAs;
  const u16* Br = Bt + (size_t)rim * (2560ull * 1024);
  const float* bip = bp + (size_t)rim * 2560;

  const int t = threadIdx.x;
  const int w = t >> 6, lane = t & 63;
  const int lrow = lane & 15, lk = lane >> 4;
  const int wr = w >> 2, wc = w & 3;             // 2M x 4N; wave tile 128x64

  f32x4 acc[8][4] = {};

  // ---- staging precompute ----
  // A-unit chunk (1/thread): c = t; row' = c>>2 in [0,128); su2 = (c&3)^((c>>3)&3);
  //   actual row(h=0) = (row'&63) + (row'>>6)*128;  h=1 adds +64.
  const int aR = ((t >> 2) & 63) + (((t >> 2) >> 6) << 7);
  const int aSu = (t & 3) ^ ((t >> 3) & 3);
  const u16* aBase = Ar + (size_t)(m0 + aR) * 1088 + aSu * 8;
  // B-unit chunks (2/thread): c = t, t+512; row = c>>2 in [0,256); su2 same formula.
  const u16* bBase[2];
#pragma unroll
  for (int i = 0; i < 2; ++i) {
    const int c = t + i * 512;
    const int row = c >> 2;
    const int su = (c & 3) ^ ((c >> 3) & 3);
    bBase[i] = Br + (size_t)(n0 + row) * 1024 + su * 8;
  }
  auto stageA = [&](int h, int ks, int Tt, u16* buf) {
    gload16(aBase + (size_t)h * 64 * 1088 + Tt * 64 + ks * 32,
            buf + (ks * 2 + h) * 4096 + t * 8);
  };
  auto stageB = [&](int ks, int Tt, u16* buf) {
    gload16(bBase[0] + Tt * 64 + ks * 32, buf + 16384 + ks * 8192 + t * 8);
    gload16(bBase[1] + Tt * 64 + ks * 32, buf + 16384 + ks * 8192 + (t + 512) * 8);
  };

  constexpr int nks = 16;                        // K = 1024
  // prologue: batches s0..s3 of T0 -> buf0 (8 loads/thread outstanding)
  stageA(0, 0, 0, lds); stageB(0, 0, lds);       // s0 (3)
  stageA(1, 0, 0, lds);                          // s1 (1)
  stageA(0, 1, 0, lds); stageB(1, 0, lds);       // s2 (3)
  stageA(1, 1, 0, lds);                          // s3 (1)

  for (int T = 0; T < nks; ++T) {
    const char* tb = (const char*)(lds + (T & 1) * 32768);
    u16* nxt = lds + ((T + 1) & 1) * 32768;
    const bool st = (T + 1 < nks);

    FragU4 af[4], bfr[4];

    // ===== ph0 (ks=0, h=0): consumes s0 = {A(0,0), B(0)} =====
    asm volatile("s_waitcnt vmcnt(5)\ns_barrier" ::: "memory");
    __builtin_amdgcn_sched_barrier(0);
#pragma unroll
    for (int nf = 0; nf < 4; ++nf) {
      const int rr = wc * 64 + nf * 16 + lrow;
      bfr[nf].u4 = *(const uint4*)(tb + 32768 + rr * 64 + ((lk ^ ((rr >> 1) & 3)) << 4));
    }
#pragma unroll
    for (int mf = 0; mf < 4; ++mf) {
      const int rp = wr * 64 + mf * 16 + lrow;
      af[mf].u4 = *(const uint4*)(tb + rp * 64 + ((lk ^ ((rp >> 1) & 3)) << 4));
    }
    if (st) { stageA(0, 0, T + 1, nxt); stageB(0, T + 1, nxt); }
    __builtin_amdgcn_s_setprio(1);
#pragma unroll
    for (int mf = 0; mf < 4; ++mf)
#pragma unroll
      for (int nf = 0; nf < 4; ++nf)
        acc[mf][nf] = __builtin_amdgcn_mfma_f32_16x16x32_bf16(af[mf].v, bfr[nf].v, acc[mf][nf], 0, 0, 0);
    __builtin_amdgcn_s_setprio(0);

    // ===== ph1 (ks=0, h=1): consumes s1 = {A(0,1)} =====
    if (st) asm volatile("s_waitcnt vmcnt(7)\ns_barrier" ::: "memory");
    else    asm volatile("s_waitcnt vmcnt(4)\ns_barrier" ::: "memory");
    __builtin_amdgcn_sched_barrier(0);
#pragma unroll
    for (int mf = 0; mf < 4; ++mf) {
      const int rp = wr * 64 + mf * 16 + lrow;
      af[mf].u4 = *(const uint4*)(tb + 8192 + rp * 64 + ((lk ^ ((rp >> 1) & 3)) << 4));
    }
    if (st) stageA(1, 0, T + 1, nxt);
    __builtin_amdgcn_s_setprio(1);
#pragma unroll
    for (int mf = 0; mf < 4; ++mf)
#pragma unroll
      for (int nf = 0; nf < 4; ++nf)
        acc[4 + mf][nf] = __builtin_amdgcn_mfma_f32_16x16x32_bf16(af[mf].v, bfr[nf].v, acc[4 + mf][nf], 0, 0, 0);
    __builtin_amdgcn_s_setprio(0);

    // ===== ph2 (ks=1, h=0): consumes s2 = {A(1,0), B(1)} =====
    if (st) asm volatile("s_waitcnt vmcnt(5)\ns_barrier" ::: "memory");
    else    asm volatile("s_waitcnt vmcnt(1)\ns_barrier" ::: "memory");
    __builtin_amdgcn_sched_barrier(0);
#pragma unroll
    for (int nf = 0; nf < 4; ++nf) {
      const int rr = wc * 64 + nf * 16 + lrow;
      bfr[nf].u4 = *(const uint4*)(tb + 49152 + rr * 64 + ((lk ^ ((rr >> 1) & 3)) << 4));
    }
#pragma unroll
    for (int mf = 0; mf < 4; ++mf) {
      const int rp = wr * 64 + mf * 16 + lrow;
      af[mf].u4 = *(const uint4*)(tb + 16384 + rp * 64 + ((lk ^ ((rp >> 1) & 3)) << 4));
    }
    if (st) { stageA(0, 1, T + 1, nxt); stageB(1, T + 1, nxt); }
    __builtin_amdgcn_s_setprio(1);
#pragma unroll
    for (int mf = 0; mf < 4; ++mf)
#pragma unroll
      for (int nf = 0; nf < 4; ++nf)
        acc[mf][nf] = __builtin_amdgcn_mfma_f32_16x16x32_bf16(af[mf].v, bfr[nf].v, acc[mf][nf], 0, 0, 0);
    __builtin_amdgcn_s_setprio(0);

    // ===== ph3 (ks=1, h=1): consumes s3 = {A(1,1)} =====
    if (st) asm volatile("s_waitcnt vmcnt(7)\ns_barrier" ::: "memory");
    else    asm volatile("s_waitcnt vmcnt(0)\ns_barrier" ::: "memory");
    __builtin_amdgcn_sched_barrier(0);
#pragma unroll
    for (int mf = 0; mf < 4; ++mf) {
      const int rp = wr * 64 + mf * 16 + lrow;
      af[mf].u4 = *(const uint4*)(tb + 24576 + rp * 64 + ((lk ^ ((rp >> 1) & 3)) << 4));
    }
    if (st) stageA(1, 1, T + 1, nxt);
    __builtin_amdgcn_s_setprio(1);
#pragma unroll
    for (int mf = 0; mf < 4; ++mf)
#pragma unroll
      for (int nf = 0; nf < 4; ++nf)
        acc[4 + mf][nf] = __builtin_amdgcn_mfma_f32_16x16x32_bf16(af[mf].v, bfr[nf].v, acc[4 + mf][nf], 0, 0, 0);
    __builtin_amdgcn_s_setprio(0);
  }

  // epilogue: 64-col group = {i,f,g,o} x 16 units. acc[idx] <-> row h*64 + mfq*16
  const int nb = n0 + wc * 64;
  const int u = ((nb >> 6) << 4) + lrow;
  if (u < 600) {
    const float b_i = bip[nb + lrow];
    const float b_f = bip[nb + 16 + lrow];
    const float b_g = bip[nb + 32 + lrow];
    const float b_o = bip[nb + 48 + lrow];
#pragma unroll
    for (int idx = 0; idx < 8; ++idx)
#pragma unroll
      for (int r2 = 0; r2 < 4; ++r2) {
        const int m = m0 + wr * 128 + (idx >> 2) * 64 + (idx & 3) * 16 + 4 * lk + r2;
        const float iv = acc[idx][0][r2] + b_i;
        const float fv = acc[idx][1][r2] + b_f;
        const float gv = acc[idx][2][r2] + b_g;
        const float ov = acc[idx][3][r2] + b_o;
        const size_t off = (size_t)m * 3600 + rim * 600 + u;
        const float cprev = cs[off];
        const float cv = sigmoidf_(fv) * cprev + sigmoidf_(iv) * tanhf_(gv);
        const float hv = sigmoidf_(ov) * tanhf_(cv);
        const float mk = mask[(size_t)m * 6 + rim];
        c_upd[off] = (mk != 0.f) ? cv : cprev;
        h_upd[off] = hv;
        hnbf[(size_t)m * kHnS + rim * 600 + u] = f2b(hv);
      }
  }
}

// ================= weight megapack =================
__device__ void pack_wt_body(float (*tile)[65], int bx, int by, int rim,
    const float* __restrict__ i1, long s1, const float* __restrict__ i2, long s2,
    int K1, int Ktot, int ldin, int Nreal,
    u16* __restrict__ out, long so, int Kpad, int gateperm, int tid)
{
  i1 += (size_t)rim * s1;
  if (i2) i2 += (size_t)rim * s2;
  u16* o = out + (size_t)rim * so;
  const int n0 = bx * 64, k0 = by * 64;
  const int lane = tid & 63, qq = tid >> 6;
  const int n = n0 + lane;
  int col;
  if (gateperm) {
    const int g = (n >> 4) & 3, u = ((n >> 6) << 4) + (n & 15);
    col = (u < 600) ? g * 600 + u : -1;
  } else {
    col = (n < Nreal) ? n : -1;
  }
#pragma unroll
  for (int i = 0; i < 16; ++i) {
    const int kk = qq + 4 * i;
    const int k = k0 + kk;
    float v = 0.f;
    if (col >= 0) {
      if (k < K1) v = i1[(size_t)k * ldin + col];
      else if (k < Ktot) v = i2[(size_t)(k - K1) * ldin + col];
    }
    tile[kk][lane] = v;
  }
  __syncthreads();
#pragma unroll
  for (int i = 0; i < 16; ++i) {
    const int nn = qq + 4 * i;
    const int k = k0 + lane;
    if (k < Kpad) o[(size_t)(n0 + nn) * Kpad + k] = f2b(tile[lane][nn]);
  }
}

__global__ __launch_bounds__(256) void megapack_w(
    const float* __restrict__ Wk, const float* __restrict__ Wv,
    const float* __restrict__ Wkc, const float* __restrict__ Wqc, const float* __restrict__ Wvc,
    const float* __restrict__ Wq, const float* __restrict__ Wout,
    const float* __restrict__ lstm_k, const float* __restrict__ lstm_r,
    u16* __restrict__ WkvT, u16* __restrict__ WcomT, u16* __restrict__ WqT,
    u16* __restrict__ WoutT, u16* __restrict__ LstmT)
{
  __shared__ float tile[64][65];
  const int id = blockIdx.x, t = threadIdx.x;
  if (id < 3840) {                 // LSTM (40,16,6), N rows 2560 (2432+ zero), Kpad 1024
    const int bx = id % 40, by = (id / 40) % 16, bz = id / 640;
    pack_wt_body(tile, bx, by, bz, lstm_k, 400l*2400, lstm_r, 600l*2400,
                 400, 1000, 2400, 2400, LstmT, 2560l*1024, 1024, 1, t);
  } else if (id < 4260) {          // Wout (10,7,6), Kpad 448
    const int i2 = id - 3840;
    const int bx = i2 % 10, by = (i2 / 10) % 7, bz = i2 / 70;
    pack_wt_body(tile, bx, by, bz, Wout, 400l*600, nullptr, 0,
                 400, 400, 600, 600, WoutT, 640l*448, 448, 0, t);
  } else if (id < 4500) {          // Wq (4,10,6), Kpad 640
    const int i3 = id - 4260;
    const int bx = i3 % 4, by = (i3 / 4) % 10, bz = i3 / 40;
    pack_wt_body(tile, bx, by, bz, Wq, 600l*256, nullptr, 0,
                 600, 600, 256, 256, WqT, 256l*640, 640, 0, t);
  } else if (id < 4692) {          // kvw: [768][512], 8 elems/thread
    const int e8 = ((id - 4500) * 256 + t) * 8;
    const int n = e8 >> 9, k0 = e8 & 511;
    u16 st[8];
#pragma unroll
    for (int j = 0; j < 8; ++j) {
      const int k = k0 + j;
      float v = 0.f;
      if (n < 256) v = Wk[(size_t)k * 256 + n];
      else if (n < 656) {
        const float* p = Wv + (size_t)k * 1600 + (n - 256);
        v = 0.25f * (p[0] + p[400] + p[800] + p[1200]);
      }
      st[j] = f2b(v);
    }
    *(uint4*)(WkvT + e8) = *(const uint4*)st;
  } else {                         // comw: [6][768][640], 8 elems/thread
    const long long e8 = ((long long)(id - 4692) * 256 + t) * 8;
    const int rim = (int)(e8 / 491520);
    const int rem = (int)(e8 % 491520);
    const int n = rem / 640, k0 = rem % 640;
    u16 st[8];
#pragma unroll
    for (int j = 0; j < 8; ++j) {
      const int k = k0 + j;
      float v = 0.f;
      if (k < 600) {
        if (n < 128)      v = Wkc[(size_t)rim * 76800 + (size_t)k * 128 + n];
        else if (n < 256) v = Wqc[(size_t)rim * 76800 + (size_t)k * 128 + (n - 128)];
        else if (n < 656) v = Wvc[(size_t)rim * 240000 + (size_t)k * 400 + (n - 256)];
      }
      st[j] = f2b(v);
    }
    *(uint4*)(WcomT + e8) = *(const uint4*)st;
  }
}

// ================= activation megapack =================
__global__ __launch_bounds__(256) void megapack_act(
    const float* __restrict__ inputs, const float* __restrict__ hs,
    const float* __restrict__ lstm_b, const float* __restrict__ bk, const float* __restrict__ bv,
    u16* __restrict__ xbf, u16* __restrict__ gA, float* __restrict__ bp, float* __restrict__ bkv,
    u16* __restrict__ hnbf)
{
  __shared__ float row[3600];
  const int id = blockIdx.x, t = threadIdx.x;
  if (id < 4096) {                 // gA hs-part cols 400..1087 (zero beyond 600-wide hs)
    const int b = id;
    for (int i = t; i < 3600; i += 256) row[i] = hs[(size_t)b * 3600 + i];
    __syncthreads();
    for (int c = t; c < 516; c += 256) {          // 6 rims x 86 chunks (688 cols)
      const int rim = c / 86;
      const int j = (c % 86) * 8;
      u16 v[8];
#pragma unroll
      for (int k = 0; k < 8; ++k) {
        const int col = j + k;
        v[k] = (col < 600) ? f2b(row[rim * 600 + col]) : (u16)0;
      }
      *(uint4*)(gA + (size_t)rim * kGAs + (size_t)b * 1088 + 400 + j) = *(const uint4*)v;
    }
    // zero hnbf tail cols 3600..3647 (read by cqv GEMM's padded-K window at rim 5)
    if (t < 6) {
      u16 z[8] = {0,0,0,0,0,0,0,0};
      *(uint4*)(hnbf + (size_t)b * kHnS + 3600 + t * 8) = *(const uint4*)z;
    }
  } else if (id < 5120) {          // xbf
    const int e8 = ((id - 4096) * 256 + t) * 8;
    const int b = e8 >> 9, c0 = e8 & 511;
    const float* src = inputs + (size_t)b * 518 + c0;
    u16 st[8];
#pragma unroll
    for (int j = 0; j < 8; ++j) st[j] = f2b(src[j]);
    *(uint4*)(xbf + e8) = *(const uint4*)st;
  } else {                         // misc
    const int tt = (id - 5120) * 256 + t;
    if (tt < 6 * 2560) {
      const int rim = tt / 2560, p = tt % 2560;
      const int g = (p >> 4) & 3, u = ((p >> 6) << 4) + (p & 15);
      bp[tt] = (u < 600) ? lstm_b[(size_t)rim * 2400 + g * 600 + u] : 0.f;
    }
    if (tt < 768) {
      float v = 0.f;
      if (tt < 256) v = bk[tt];
      else if (tt < 656) { const int j2 = tt - 256; v = 0.25f * (bv[j2] + bv[j2+400] + bv[j2+800] + bv[j2+1200]); }
      bkv[tt] = v;
    }
  }
}

// ============ scores + softmax + top-k mask + rnn_in (-> gA cols 0..399) ============
__global__ __launch_bounds__(256) void score_kernel(
    const float* __restrict__ inputs, const u16* __restrict__ qlayb,
    const u16* __restrict__ kvb, const float* __restrict__ bk,
    const float* __restrict__ bkv,
    float* __restrict__ maskout, u16* __restrict__ gA)
{
  const int b = blockIdx.x;
  const int t = threadIdx.x;
  __shared__ float red[4][12];
  __shared__ float sprob[12];
  __shared__ float smask[6];

  const float k0v = b2f(kvb[(size_t)b * 768 + t]);
  const float bkv_ = bk[t];
  float part[12];
#pragma unroll
  for (int n = 0; n < 6; ++n) {
    const float q = b2f(qlayb[(size_t)b * 1536 + n * 256 + t]);
    part[2 * n]     = q * k0v;
    part[2 * n + 1] = q * bkv_;
  }
#pragma unroll
  for (int off = 32; off > 0; off >>= 1)
#pragma unroll
    for (int i = 0; i < 12; ++i)
      part[i] += __shfl_down(part[i], off);
  const int wave = t >> 6, lane = t & 63;
  if (lane == 0)
#pragma unroll
    for (int i = 0; i < 12; ++i) red[wave][i] = part[i];
  __syncthreads();
  if (t < 12) red[0][t] = (red[0][t] + red[1][t] + red[2][t] + red[3][t]) * (1.0f / 32.0f);
  __syncthreads();
  if (t < 6) {
    const float s0 = red[0][2 * t], s1 = red[0][2 * t + 1];
    const float mx = fmaxf(s0, s1);
    const float e0 = __expf(s0 - mx), e1 = __expf(s1 - mx);
    const float inv = 1.f / (e0 + e1);
    sprob[2 * t] = e0 * inv;
    sprob[2 * t + 1] = e1 * inv;
    const float* rd = inputs + (size_t)b * 518 + 512;
    const float mine = rd[t];
    int rank = 0;
#pragma unroll
    for (int j = 0; j < 6; ++j) {
      const float o = rd[j];
      rank += (o > mine) || (o == mine && j < t);
    }
    const float mk = (rank < 4) ? 1.f : 0.f;
    smask[t] = mk;
    maskout[(size_t)b * 6 + t] = mk;
  }
  __syncthreads();
  for (int c = t; c < 300; c += 256) {
    const int n = c / 50;
    const int v = (c % 50) * 8;
    const float p0 = sprob[2 * n], p1 = sprob[2 * n + 1], mk = smask[n];
    u16 st[8];
#pragma unroll
    for (int k = 0; k < 8; ++k)
      st[k] = f2b((p0 * b2f(kvb[(size_t)b * 768 + 256 + v + k]) + p1 * bkv[256 + v + k]) * mk);
    *reinterpret_cast<uint4*>(gA + (size_t)n * kGAs + (size_t)b * 1088 + v) =
        *reinterpret_cast<const uint4*>(st);
  }
}

// ============ comm attention ============
__global__ __launch_bounds__(256) void comm_kernel(
    const u16* __restrict__ cqv, u16* __restrict__ ctx)
{
  const int b = blockIdx.x, t = threadIdx.x;
  __shared__ float skc[768], sqc[768], svc[2400];
  __shared__ float spc[4][6][6];
  for (int i = t * 4; i < 4608; i += 1024) {
    const ushort4 u4 = *reinterpret_cast<const ushort4*>(cqv + (size_t)b * 4608 + i);
    const u16 uu[4] = {u4.x, u4.y, u4.z, u4.w};
#pragma unroll
    for (int j = 0; j < 4; ++j) {
      const int ii = i + j;
      const int m = ii / 768, c = ii % 768;
      const float v = b2f(uu[j]);
      if (c < 128) skc[m * 128 + c] = v;
      else if (c < 256) sqc[m * 128 + (c - 128)] = v;
      else if (c < 656) svc[m * 400 + (c - 256)] = v;
    }
  }
  __syncthreads();
  if (t < 144) {
    const int h = t / 36, n = (t % 36) / 6, m = t % 6;
    float s = 0.f;
#pragma unroll
    for (int d = 0; d < 32; ++d) s += sqc[n * 128 + h * 32 + d] * skc[m * 128 + h * 32 + d];
    spc[h][n][m] = s * 0.17677669529663687f;
  }
  __syncthreads();
  if (t < 24) {
    const int h = t / 6, n = t % 6;
    float mx = -3.0e38f;
#pragma unroll
    for (int m = 0; m < 6; ++m) mx = fmaxf(mx, spc[h][n][m]);
    float e[6], sum = 0.f;
#pragma unroll
    for (int m = 0; m < 6; ++m) { e[m] = __expf(spc[h][n][m] - mx); sum += e[m]; }
    const float inv = 1.f / sum;
#pragma unroll
    for (int m = 0; m < 6; ++m) spc[h][n][m] = e[m] * inv;
  }
  __syncthreads();
  for (int base = t * 4; base < 2400; base += 1024) {
    const int n = base / 400, rr = base % 400, h = rr / 100, v = rr % 100;
    ushort4 st;
    float s0 = 0.f, s1 = 0.f, s2 = 0.f, s3 = 0.f;
#pragma unroll
    for (int m = 0; m < 6; ++m) {
      const float p = spc[h][n][m];
      const float* vm = &svc[m * 400 + h * 100 + v];
      s0 += p * vm[0]; s1 += p * vm[1]; s2 += p * vm[2]; s3 += p * vm[3];
    }
    st.x = f2b(s0); st.y = f2b(s1); st.z = f2b(s2); st.w = f2b(s3);
    *reinterpret_cast<ushort4*>(ctx + (size_t)b * 2400 + base) = st;
  }
}

// ================= launch =================
extern "C" void kernel_launch(void* const* d_in, const int* in_sizes, int n_in,
                              void* d_out, int out_size, void* d_ws, size_t ws_size,
                              hipStream_t stream) {
  const float* inputs = (const float*)d_in[0];
  const float* hs     = (const float*)d_in[1];
  const float* cs     = (const float*)d_in[2];
  const float* Wk     = (const float*)d_in[3];
  const float* bk     = (const float*)d_in[4];
  const float* Wv     = (const float*)d_in[5];
  const float* bv     = (const float*)d_in[6];
  const float* Wq     = (const float*)d_in[7];
  const float* lstm_k = (const float*)d_in[8];
  const float* lstm_r = (const float*)d_in[9];
  const float* lstm_b = (const float*)d_in[10];
  const float* Wkc    = (const float*)d_in[11];
  const float* Wvc    = (const float*)d_in[12];
  const float* Wqc    = (const float*)d_in[13];
  const float* Wout   = (const float*)d_in[14];

  float* out = (float*)d_out;
  float* out_state = out;
  float* h_upd = out + kOS;
  float* c_upd = out + 2 * kOS;
  u16*   hnbf  = (u16*)d_out;     // scratch alias in out_state slot (stride kHnS rows)

  char* wsb = (char*)d_ws;
  u16* WkvT  = (u16*)(wsb + oWkvT);
  u16* WqT   = (u16*)(wsb + oWqT);
  u16* WcomT = (u16*)(wsb + oWcomT);
  u16* WoutT = (u16*)(wsb + oWoutT);
  u16* LstmT = (u16*)(wsb + oLstmT);
  float* bp    = (float*)(wsb + oBp);
  float* bkv   = (float*)(wsb + oBkv);
  float* maskf = (float*)(wsb + oMask);
  u16* gA    = (u16*)(wsb + oGA);
  u16* kvb   = (u16*)(wsb + oKV);
  u16* xbf   = (u16*)(wsb + oXbf);
  u16* qlayb = (u16*)(wsb + oQlay);
  u16* cqvb  = (u16*)(wsb + oCqv);
  u16* ctxb  = (u16*)(wsb + oCtx);

  dim3 B256(256);

  // ---- packs (2 launches) ----
  megapack_w<<<6132, B256, 0, stream>>>(Wk, Wv, Wkc, Wqc, Wvc, Wq, Wout, lstm_k, lstm_r,
                                        WkvT, WcomT, WqT, WoutT, LstmT);
  megapack_act<<<5180, B256, 0, stream>>>(inputs, hs, lstm_b, bk, bv, xbf, gA, bp, bkv, hnbf);

  // ---- kv = [x@Wk+bk | x@Wvavg+bvavg]  (N=656, K=512, nks=8; 192 tiles) ----
  gemm64<0><<<dim3(192), B256, 0, stream>>>(xbf, 512, 0, WkvT, 0, 512,
      kvb, 768, 0, bkv, 0, 656, 8, 1, 6,
      nullptr, nullptr, nullptr, nullptr);
  // ---- qlay (N=256/rim, K=640 w/ zero tail, nks=10; 384 tiles) ----
  gemm64<0><<<dim3(384), B256, 0, stream>>>(gA + 400, 1088, (long)kGAs, WqT, 256l*640, 640,
      qlayb, 1536, 256, nullptr, 0, 256, 10, 1, 2,
      nullptr, nullptr, nullptr, nullptr);

  score_kernel<<<4096, B256, 0, stream>>>(inputs, qlayb, kvb, bk, bkv, maskf, gA);

  // ---- gates (M=4096, N=2560 pad, K=1024) + fused LSTM; 256² consumption-aligned pipeline ----
  gates256<<<dim3(960), dim3(512), 0, stream>>>(gA, LstmT, bp, cs, maskf, c_upd, h_upd, hnbf);

  // ---- comm projections fused: [kc|qc|vc] (N=656/rim, K=640 w/ zero tail, nks=10) ----
  gemm64<0><<<dim3(1152), B256, 0, stream>>>(hnbf, kHnS, 600, WcomT, 768l*640, 640,
      cqvb, 4608, 768, nullptr, 0, 656, 10, 1, 6,
      nullptr, nullptr, nullptr, nullptr);

  comm_kernel<<<4096, B256, 0, stream>>>(cqvb, ctxb);

  // ---- final: h_comm = ctx@Wout + h_new; masked select (N=600, K=448 w/ zero tail, nks=7) ----
  gemm64<1><<<dim3(960), B256, 0, stream>>>(ctxb, 2400, 400, WoutT, 640l*448, 448,
      nullptr, 0, 0, nullptr, 0, 600, 7, 0, 5,
      maskf, h_upd, hs, out_state);
}

// Round 16
// 561.647 us; speedup vs baseline: 1.0195x; 1.0195x over previous
//
#include <hip/hip_runtime.h>

namespace {
typedef unsigned short u16;
typedef __attribute__((ext_vector_type(8))) __bf16 bf16x8;
typedef __attribute__((ext_vector_type(4))) float f32x4;

constexpr long long kB  = 4096;
constexpr long long kOS = kB * 3600;
constexpr size_t kGAs = 4096ull * 1088;   // per-rim gA stride (elems), row = 1088
constexpr int kHnS = 3648;                // hnbf row stride (u16), cols 3600-3647 zeroed

// ---- ws byte offsets ----
constexpr size_t oWkvT  = 0;                               // bf16 [768][512]
constexpr size_t oWqT   = oWkvT  + 768ull*512*2;           // bf16 [6][256][640]
constexpr size_t oWcomT = oWqT   + 6ull*256*640*2;         // bf16 [6][768][640]
constexpr size_t oWoutT = oWcomT + 6ull*768*640*2;         // bf16 [6][640][448]
constexpr size_t oLstmT = oWoutT + 6ull*640*448*2;         // bf16 [6][2560][1024] (rows 2432+ zero)
constexpr size_t oBp    = oLstmT + 6ull*2560*1024*2;       // f32 [6][2560]
constexpr size_t oBkv   = oBp    + 6ull*2560*4;            // f32 [768]
constexpr size_t oMask  = oBkv   + 768*4;                  // f32 [4096][6]
constexpr size_t oArena = oMask  + 4096ull*6*4;
// phase-1 arena
constexpr size_t oGA    = oArena;                          // bf16 [6][4096][1088] (rnn|hs|pad0)
constexpr size_t oKV    = oGA   + 6ull*kGAs*2;             // bf16 [4096][768]
constexpr size_t oXbf   = oKV   + 4096ull*768*2;           // bf16 [4096][512]
constexpr size_t oQlay  = oXbf;                            // bf16 [4096][1536], overlays xbf AFTER kv gemm
// phase-2 overlay (phase-1 arena dead by then)
constexpr size_t oCqv   = oArena;                          // bf16 [4096][4608]
constexpr size_t oCtx   = oCqv  + 4096ull*4608*2;          // bf16 [4096][2400]+64
}

__device__ __forceinline__ u16 f2b(float f) {
  union { float f; unsigned u; } x; x.f = f;
  unsigned r = (x.u + 0x7fffu + ((x.u >> 16) & 1u)) >> 16;
  return (u16)r;
}
__device__ __forceinline__ float b2f(u16 u) {
  union { unsigned u; float f; } x; x.u = ((unsigned)u) << 16;
  return x.f;
}
__device__ __forceinline__ float sigmoidf_(float x) { return 1.f / (1.f + __expf(-x)); }
__device__ __forceinline__ float tanhf_(float x) {
  const float e = __expf(2.f * x);
  return 1.f - 2.f / (e + 1.f);
}

__device__ __forceinline__ void gload16(const void* g, void* l) {
  __builtin_amdgcn_global_load_lds((const __attribute__((address_space(1))) void*)g,
                                   (__attribute__((address_space(3))) void*)l, 16, 0, 0);
}

union FragU4 { uint4 u4; bf16x8 v; };

// ====== unified 128x128 bf16 MFMA GEMM, BK=64, 2-buf stage-early (r7 core, proven) ======
// MODE 0: C=A*B(+bias). MODE 1: final (mask select, 2 outputs).
template<int MODE>
__global__ __launch_bounds__(256, 2) void gemm64(
    const u16* __restrict__ A, int lda, long strideA,
    const u16* __restrict__ Bt, long strideB, int Kpad,
    void* __restrict__ C, int ldc, int strideC,
    const float* __restrict__ bias, int strideBias,
    int N, int nks, int storeBf16, int nx,
    const float* __restrict__ mask, float* __restrict__ h_upd,
    const float* __restrict__ hs_in, float* __restrict__ out_state)
{
  __shared__ __align__(16) u16 lds[2 * 16384];

  const int nwg = gridDim.x;
  const int orig = blockIdx.x;
  int wgid;
  {
    const int q = nwg >> 3, r = nwg & 7;
    const int xcd = orig & 7, bidx = orig >> 3;
    wgid = (xcd < r ? xcd * (q + 1) : r * (q + 1) + (xcd - r) * q) + bidx;
  }
  const int xt = wgid % nx;
  const int t2 = wgid / nx;
  const int mt = t2 & 31;
  const int rim = t2 >> 5;
  const int m0 = mt * 128, n0 = xt * 128;

  A += (size_t)rim * strideA;
  Bt += (size_t)rim * strideB;
  if (bias) bias += (size_t)rim * strideBias;

  const int t = threadIdx.x;
  const int w = t >> 6, lane = t & 63;
  const int lrow = lane & 15, lk = lane >> 4;
  const int wr = w >> 1, wc = w & 1;

  f32x4 acc[4][4] = {};

  const u16* aS[4]; const u16* bS[4]; int cC[4];
#pragma unroll
  for (int i = 0; i < 4; ++i) {
    const int c = t + i * 256;
    const int row = c >> 3, slot = c & 7;
    cC[i] = c;
    aS[i] = A  + (size_t)(m0 + row) * lda  + ((slot ^ (row & 7)) << 3);
    bS[i] = Bt + (size_t)(n0 + row) * Kpad + ((slot ^ (row & 7)) << 3);
  }
  auto stage = [&](u16* dst) {
#pragma unroll
    for (int i = 0; i < 4; ++i) gload16(aS[i], dst + (size_t)cC[i] * 8);
#pragma unroll
    for (int i = 0; i < 4; ++i) gload16(bS[i], dst + 8192 + (size_t)cC[i] * 8);
#pragma unroll
    for (int i = 0; i < 4; ++i) { aS[i] += 64; bS[i] += 64; }
  };

  stage(lds);
  asm volatile("s_waitcnt vmcnt(0)" ::: "memory");
  __builtin_amdgcn_s_barrier();

  for (int s = 0; s < nks; ++s) {
    const bool more = (s + 1 < nks);
    if (more) stage(lds + ((s + 1) & 1) * 16384);
    __builtin_amdgcn_sched_barrier(0);
    const char* Ab = (const char*)(lds + (s & 1) * 16384);
    const char* Bb = Ab + 16384;
#pragma unroll
    for (int ks = 0; ks < 2; ++ks) {
      FragU4 af[4], bf4[4];
#pragma unroll
      for (int mf = 0; mf < 4; ++mf) {
        const int rr = wr * 64 + mf * 16 + lrow;
        af[mf].u4 = *(const uint4*)(Ab + rr * 128 + ((((ks << 2) | lk) ^ (rr & 7)) << 4));
      }
#pragma unroll
      for (int nf = 0; nf < 4; ++nf) {
        const int rr = wc * 64 + nf * 16 + lrow;
        bf4[nf].u4 = *(const uint4*)(Bb + rr * 128 + ((((ks << 2) | lk) ^ (rr & 7)) << 4));
      }
#pragma unroll
      for (int mf = 0; mf < 4; ++mf)
#pragma unroll
        for (int nf = 0; nf < 4; ++nf)
          acc[mf][nf] = __builtin_amdgcn_mfma_f32_16x16x32_bf16(af[mf].v, bf4[nf].v, acc[mf][nf], 0, 0, 0);
    }
    if (more) {
      asm volatile("s_waitcnt vmcnt(0)" ::: "memory");
      __builtin_amdgcn_s_barrier();
    }
  }

  if (MODE == 0) {
    float* Cf = (float*)C + (size_t)rim * strideC;
    u16*   Cu = (u16*)C + (size_t)rim * strideC;
#pragma unroll
    for (int mf = 0; mf < 4; ++mf)
#pragma unroll
      for (int r2 = 0; r2 < 4; ++r2) {
        const int m = m0 + wr * 64 + mf * 16 + 4 * lk + r2;
#pragma unroll
        for (int nf = 0; nf < 4; ++nf) {
          const int col = n0 + wc * 64 + nf * 16 + lrow;
          if (col < N) {
            float v = acc[mf][nf][r2];
            if (bias) v += bias[col];
            const size_t off = (size_t)m * ldc + col;
            if (storeBf16) Cu[off] = f2b(v); else Cf[off] = v;
          }
        }
      }
  } else {
#pragma unroll
    for (int mf = 0; mf < 4; ++mf)
#pragma unroll
      for (int r2 = 0; r2 < 4; ++r2) {
        const int m = m0 + wr * 64 + mf * 16 + 4 * lk + r2;
        const float mk = mask[(size_t)m * 6 + rim];
#pragma unroll
        for (int nf = 0; nf < 4; ++nf) {
          const int col = n0 + wc * 64 + nf * 16 + lrow;
          if (col < 600) {
            const size_t off = (size_t)m * 3600 + rim * 600 + col;
            const float v = (mk != 0.f) ? (acc[mf][nf][r2] + h_upd[off]) : hs_in[off];
            h_upd[off] = v;
            out_state[off] = v;
          }
        }
      }
  }
}

// ====== gates: 256x256 bf16 MFMA + fused LSTM, 4-phase counted-vmcnt (r14 best) ======
// 512 thr = 8 waves (2M x 4N), wave 128x64 (acc 8x4). LDS 2 buf x 64KB; per buf, four
// 16KB k-half units: A-kh0 @0, A-kh1 @8192(u16), B-kh0 @16384, B-kh1 @24576.
// Unit layout: 128 LDS-rows x 128B; LDS-row r packs global rows 2r,2r+1; slot8 s8:
// global row = 2r+(s8>>2), logical k-16B su2 = (s8&3) ^ (r&3)  (2-bit XOR swizzle).
// -> READS (b128, 16 lanes over 16 consecutive rows): all 8 (parity, r&3-combo) slots
//    distinct -> 2 lanes/bank = free.  STAGING: chunk c dest = half_base + c*16B,
//    strictly lane-linear (gload_lds wave-uniform-base+lane*16 requirement, m104) with
//    the permutation applied on the per-lane GLOBAL source (m173 pattern).
// Schedule: 4 phases/K-tile (ks x mf-half); phase stages one unit of tile T+1; waits
// vmcnt(4) at ph0/ph2 (oldest unit pair of 8 outstanding, issued 3-4 phases earlier);
// vmcnt(0) only at final tile ph2. Wait fused with s_barrier in one asm; setprio (T5).
__global__ __launch_bounds__(512, 2) void gates256(
    const u16* __restrict__ A, const u16* __restrict__ Bt,
    const float* __restrict__ bp, const float* __restrict__ cs,
    const float* __restrict__ mask,
    float* __restrict__ c_upd, float* __restrict__ h_upd, u16* __restrict__ hnbf)
{
  __shared__ __align__(16) u16 lds[2 * 32768];   // 2 buf x 64KB

  const int orig = blockIdx.x;                   // grid 960: q=120, r=0
  const int wgid = (orig & 7) * 120 + (orig >> 3);
  const int rim = wgid / 160;
  const int rem = wgid % 160;
  const int half = rem / 80;
  const int r2d = rem % 80;
  const int mt = r2d / 5;
  const int xt = half * 5 + r2d % 5;
  const int m0 = mt * 256, n0 = xt * 256;

  const u16* Ar = A + (size_t)rim * kGAs;
  const u16* Br = Bt + (size_t)rim * (2560ull * 1024);
  const float* bip = bp + (size_t)rim * 2560;

  const int t = threadIdx.x;
  const int w = t >> 6, lane = t & 63;
  const int lrow = lane & 15, lk = lane >> 4;
  const int wr = w >> 2, wc = w & 3;             // 2M x 4N; wave tile 128x64

  f32x4 acc[8][4] = {};

  // staging precompute: per unit 1024 chunks; thread owns c = t, t+512.
  // chunk c: LDS dest = half_base + c*8 (u16) [lane-linear]. Content decode:
  //   grow = 2*(c>>3) + ((c>>2)&1);  su2 = (c&3) ^ ((c>>3)&3)   (k-16B within half)
  const u16* aP[2]; const u16* bP[2]; int dC[2];
#pragma unroll
  for (int i = 0; i < 2; ++i) {
    const int c = t + i * 512;
    const int grow = 2 * (c >> 3) + ((c >> 2) & 1);
    const int su2 = (c & 3) ^ ((c >> 3) & 3);
    dC[i] = c * 8;
    aP[i] = Ar + (size_t)(m0 + grow) * 1088 + su2 * 8;
    bP[i] = Br + (size_t)(n0 + grow) * 1024 + su2 * 8;
  }
  auto stageU = [&](int isB, int kh, int ktile, u16* buf) {
    u16* dst = buf + (isB ? 16384 : 0) + kh * 8192;
    const int go = ktile * 64 + kh * 32;
#pragma unroll
    for (int i = 0; i < 2; ++i)
      gload16((isB ? bP[i] : aP[i]) + go, dst + dC[i]);
  };

  constexpr int nks = 16;                        // K = 1024
  // prologue: 4 units of T0 -> buf0 (8 loads/thread outstanding)
  stageU(0, 0, 0, lds); stageU(1, 0, 0, lds); stageU(0, 1, 0, lds); stageU(1, 1, 0, lds);

  for (int T = 0; T < nks; ++T) {
    const char* tb = (const char*)(lds + (T & 1) * 32768);
    const char* Ah[2] = { tb, tb + 16384 };            // byte bases, ks=0/1
    const char* Bh[2] = { tb + 32768, tb + 49152 };
    u16* nxt = lds + ((T + 1) & 1) * 32768;
    const bool st = (T + 1 < nks);

    FragU4 af[4], bfr[4];

    // ===== ph0: ks=0, mf-half 0 =====  (needs A-kh0,B-kh0 of T = oldest 4 loads)
    asm volatile("s_waitcnt vmcnt(4)\ns_barrier" ::: "memory");
    __builtin_amdgcn_sched_barrier(0);
#pragma unroll
    for (int nf = 0; nf < 4; ++nf) {
      const int rr = wc * 64 + nf * 16 + lrow;
      bfr[nf].u4 = *(const uint4*)(Bh[0] + (rr >> 1) * 128 +
                   ((((rr & 1) << 2) | (lk ^ ((rr >> 1) & 3))) << 4));
    }
#pragma unroll
    for (int mf = 0; mf < 4; ++mf) {
      const int rr = wr * 128 + mf * 16 + lrow;
      af[mf].u4 = *(const uint4*)(Ah[0] + (rr >> 1) * 128 +
                  ((((rr & 1) << 2) | (lk ^ ((rr >> 1) & 3))) << 4));
    }
    if (st) stageU(0, 0, T + 1, nxt);
    __builtin_amdgcn_s_setprio(1);
#pragma unroll
    for (int mf = 0; mf < 4; ++mf)
#pragma unroll
      for (int nf = 0; nf < 4; ++nf)
        acc[mf][nf] = __builtin_amdgcn_mfma_f32_16x16x32_bf16(af[mf].v, bfr[nf].v, acc[mf][nf], 0, 0, 0);
    __builtin_amdgcn_s_setprio(0);

    // ===== ph1: ks=0, mf-half 1 =====
#pragma unroll
    for (int mf = 0; mf < 4; ++mf) {
      const int rr = wr * 128 + 64 + mf * 16 + lrow;
      af[mf].u4 = *(const uint4*)(Ah[0] + (rr >> 1) * 128 +
                  ((((rr & 1) << 2) | (lk ^ ((rr >> 1) & 3))) << 4));
    }
    if (st) stageU(1, 0, T + 1, nxt);
    __builtin_amdgcn_s_setprio(1);
#pragma unroll
    for (int mf = 0; mf < 4; ++mf)
#pragma unroll
      for (int nf = 0; nf < 4; ++nf)
        acc[4 + mf][nf] = __builtin_amdgcn_mfma_f32_16x16x32_bf16(af[mf].v, bfr[nf].v, acc[4 + mf][nf], 0, 0, 0);
    __builtin_amdgcn_s_setprio(0);

    // ===== ph2: ks=1, mf-half 0 =====  (needs A-kh1,B-kh1 of T = oldest 4 of 8)
    if (st) asm volatile("s_waitcnt vmcnt(4)\ns_barrier" ::: "memory");
    else    asm volatile("s_waitcnt vmcnt(0)\ns_barrier" ::: "memory");
    __builtin_amdgcn_sched_barrier(0);
#pragma unroll
    for (int nf = 0; nf < 4; ++nf) {
      const int rr = wc * 64 + nf * 16 + lrow;
      bfr[nf].u4 = *(const uint4*)(Bh[1] + (rr >> 1) * 128 +
                   ((((rr & 1) << 2) | (lk ^ ((rr >> 1) & 3))) << 4));
    }
#pragma unroll
    for (int mf = 0; mf < 4; ++mf) {
      const int rr = wr * 128 + mf * 16 + lrow;
      af[mf].u4 = *(const uint4*)(Ah[1] + (rr >> 1) * 128 +
                  ((((rr & 1) << 2) | (lk ^ ((rr >> 1) & 3))) << 4));
    }
    if (st) stageU(0, 1, T + 1, nxt);
    __builtin_amdgcn_s_setprio(1);
#pragma unroll
    for (int mf = 0; mf < 4; ++mf)
#pragma unroll
      for (int nf = 0; nf < 4; ++nf)
        acc[mf][nf] = __builtin_amdgcn_mfma_f32_16x16x32_bf16(af[mf].v, bfr[nf].v, acc[mf][nf], 0, 0, 0);
    __builtin_amdgcn_s_setprio(0);

    // ===== ph3: ks=1, mf-half 1 =====
#pragma unroll
    for (int mf = 0; mf < 4; ++mf) {
      const int rr = wr * 128 + 64 + mf * 16 + lrow;
      af[mf].u4 = *(const uint4*)(Ah[1] + (rr >> 1) * 128 +
                  ((((rr & 1) << 2) | (lk ^ ((rr >> 1) & 3))) << 4));
    }
    if (st) stageU(1, 1, T + 1, nxt);
    __builtin_amdgcn_s_setprio(1);
#pragma unroll
    for (int mf = 0; mf < 4; ++mf)
#pragma unroll
      for (int nf = 0; nf < 4; ++nf)
        acc[4 + mf][nf] = __builtin_amdgcn_mfma_f32_16x16x32_bf16(af[mf].v, bfr[nf].v, acc[4 + mf][nf], 0, 0, 0);
    __builtin_amdgcn_s_setprio(0);
  }

  // epilogue: 64-col group = {i,f,g,o} x 16 units (nf = gate index)
  const int nb = n0 + wc * 64;
  const int u = ((nb >> 6) << 4) + lrow;
  if (u < 600) {
    const float b_i = bip[nb + lrow];
    const float b_f = bip[nb + 16 + lrow];
    const float b_g = bip[nb + 32 + lrow];
    const float b_o = bip[nb + 48 + lrow];
#pragma unroll
    for (int mf = 0; mf < 8; ++mf)
#pragma unroll
      for (int r2 = 0; r2 < 4; ++r2) {
        const int m = m0 + wr * 128 + mf * 16 + 4 * lk + r2;
        const float iv = acc[mf][0][r2] + b_i;
        const float fv = acc[mf][1][r2] + b_f;
        const float gv = acc[mf][2][r2] + b_g;
        const float ov = acc[mf][3][r2] + b_o;
        const size_t off = (size_t)m * 3600 + rim * 600 + u;
        const float cprev = cs[off];
        const float cv = sigmoidf_(fv) * cprev + sigmoidf_(iv) * tanhf_(gv);
        const float hv = sigmoidf_(ov) * tanhf_(cv);
        const float mk = mask[(size_t)m * 6 + rim];
        c_upd[off] = (mk != 0.f) ? cv : cprev;
        h_upd[off] = hv;
        hnbf[(size_t)m * kHnS + rim * 600 + u] = f2b(hv);
      }
  }
}

// ================= weight megapack =================
__device__ void pack_wt_body(float (*tile)[65], int bx, int by, int rim,
    const float* __restrict__ i1, long s1, const float* __restrict__ i2, long s2,
    int K1, int Ktot, int ldin, int Nreal,
    u16* __restrict__ out, long so, int Kpad, int gateperm, int tid)
{
  i1 += (size_t)rim * s1;
  if (i2) i2 += (size_t)rim * s2;
  u16* o = out + (size_t)rim * so;
  const int n0 = bx * 64, k0 = by * 64;
  const int lane = tid & 63, qq = tid >> 6;
  const int n = n0 + lane;
  int col;
  if (gateperm) {
    const int g = (n >> 4) & 3, u = ((n >> 6) << 4) + (n & 15);
    col = (u < 600) ? g * 600 + u : -1;
  } else {
    col = (n < Nreal) ? n : -1;
  }
#pragma unroll
  for (int i = 0; i < 16; ++i) {
    const int kk = qq + 4 * i;
    const int k = k0 + kk;
    float v = 0.f;
    if (col >= 0) {
      if (k < K1) v = i1[(size_t)k * ldin + col];
      else if (k < Ktot) v = i2[(size_t)(k - K1) * ldin + col];
    }
    tile[kk][lane] = v;
  }
  __syncthreads();
#pragma unroll
  for (int i = 0; i < 16; ++i) {
    const int nn = qq + 4 * i;
    const int k = k0 + lane;
    if (k < Kpad) o[(size_t)(n0 + nn) * Kpad + k] = f2b(tile[lane][nn]);
  }
}

__global__ __launch_bounds__(256) void megapack_w(
    const float* __restrict__ Wk, const float* __restrict__ Wv,
    const float* __restrict__ Wkc, const float* __restrict__ Wqc, const float* __restrict__ Wvc,
    const float* __restrict__ Wq, const float* __restrict__ Wout,
    const float* __restrict__ lstm_k, const float* __restrict__ lstm_r,
    u16* __restrict__ WkvT, u16* __restrict__ WcomT, u16* __restrict__ WqT,
    u16* __restrict__ WoutT, u16* __restrict__ LstmT)
{
  __shared__ float tile[64][65];
  const int id = blockIdx.x, t = threadIdx.x;
  if (id < 3840) {                 // LSTM (40,16,6), N rows 2560 (2432+ zero), Kpad 1024
    const int bx = id % 40, by = (id / 40) % 16, bz = id / 640;
    pack_wt_body(tile, bx, by, bz, lstm_k, 400l*2400, lstm_r, 600l*2400,
                 400, 1000, 2400, 2400, LstmT, 2560l*1024, 1024, 1, t);
  } else if (id < 4260) {          // Wout (10,7,6), Kpad 448
    const int i2 = id - 3840;
    const int bx = i2 % 10, by = (i2 / 10) % 7, bz = i2 / 70;
    pack_wt_body(tile, bx, by, bz, Wout, 400l*600, nullptr, 0,
                 400, 400, 600, 600, WoutT, 640l*448, 448, 0, t);
  } else if (id < 4500) {          // Wq (4,10,6), Kpad 640
    const int i3 = id - 4260;
    const int bx = i3 % 4, by = (i3 / 4) % 10, bz = i3 / 40;
    pack_wt_body(tile, bx, by, bz, Wq, 600l*256, nullptr, 0,
                 600, 600, 256, 256, WqT, 256l*640, 640, 0, t);
  } else if (id < 4692) {          // kvw: [768][512], 8 elems/thread
    const int e8 = ((id - 4500) * 256 + t) * 8;
    const int n = e8 >> 9, k0 = e8 & 511;
    u16 st[8];
#pragma unroll
    for (int j = 0; j < 8; ++j) {
      const int k = k0 + j;
      float v = 0.f;
      if (n < 256) v = Wk[(size_t)k * 256 + n];
      else if (n < 656) {
        const float* p = Wv + (size_t)k * 1600 + (n - 256);
        v = 0.25f * (p[0] + p[400] + p[800] + p[1200]);
      }
      st[j] = f2b(v);
    }
    *(uint4*)(WkvT + e8) = *(const uint4*)st;
  } else {                         // comw: [6][768][640], 8 elems/thread
    const long long e8 = ((long long)(id - 4692) * 256 + t) * 8;
    const int rim = (int)(e8 / 491520);
    const int rem = (int)(e8 % 491520);
    const int n = rem / 640, k0 = rem % 640;
    u16 st[8];
#pragma unroll
    for (int j = 0; j < 8; ++j) {
      const int k = k0 + j;
      float v = 0.f;
      if (k < 600) {
        if (n < 128)      v = Wkc[(size_t)rim * 76800 + (size_t)k * 128 + n];
        else if (n < 256) v = Wqc[(size_t)rim * 76800 + (size_t)k * 128 + (n - 128)];
        else if (n < 656) v = Wvc[(size_t)rim * 240000 + (size_t)k * 400 + (n - 256)];
      }
      st[j] = f2b(v);
    }
    *(uint4*)(WcomT + e8) = *(const uint4*)st;
  }
}

// ================= activation megapack =================
__global__ __launch_bounds__(256) void megapack_act(
    const float* __restrict__ inputs, const float* __restrict__ hs,
    const float* __restrict__ lstm_b, const float* __restrict__ bk, const float* __restrict__ bv,
    u16* __restrict__ xbf, u16* __restrict__ gA, float* __restrict__ bp, float* __restrict__ bkv,
    u16* __restrict__ hnbf)
{
  __shared__ float row[3600];
  const int id = blockIdx.x, t = threadIdx.x;
  if (id < 4096) {                 // gA hs-part cols 400..1087 (zero beyond 600-wide hs)
    const int b = id;
    for (int i = t; i < 3600; i += 256) row[i] = hs[(size_t)b * 3600 + i];
    __syncthreads();
    for (int c = t; c < 516; c += 256) {          // 6 rims x 86 chunks (688 cols)
      const int rim = c / 86;
      const int j = (c % 86) * 8;
      u16 v[8];
#pragma unroll
      for (int k = 0; k < 8; ++k) {
        const int col = j + k;
        v[k] = (col < 600) ? f2b(row[rim * 600 + col]) : (u16)0;
      }
      *(uint4*)(gA + (size_t)rim * kGAs + (size_t)b * 1088 + 400 + j) = *(const uint4*)v;
    }
    // zero hnbf tail cols 3600..3647 (read by cqv GEMM's padded-K window at rim 5)
    if (t < 6) {
      u16 z[8] = {0,0,0,0,0,0,0,0};
      *(uint4*)(hnbf + (size_t)b * kHnS + 3600 + t * 8) = *(const uint4*)z;
    }
  } else if (id < 5120) {          // xbf
    const int e8 = ((id - 4096) * 256 + t) * 8;
    const int b = e8 >> 9, c0 = e8 & 511;
    const float* src = inputs + (size_t)b * 518 + c0;
    u16 st[8];
#pragma unroll
    for (int j = 0; j < 8; ++j) st[j] = f2b(src[j]);
    *(uint4*)(xbf + e8) = *(const uint4*)st;
  } else {                         // misc
    const int tt = (id - 5120) * 256 + t;
    if (tt < 6 * 2560) {
      const int rim = tt / 2560, p = tt % 2560;
      const int g = (p >> 4) & 3, u = ((p >> 6) << 4) + (p & 15);
      bp[tt] = (u < 600) ? lstm_b[(size_t)rim * 2400 + g * 600 + u] : 0.f;
    }
    if (tt < 768) {
      float v = 0.f;
      if (tt < 256) v = bk[tt];
      else if (tt < 656) { const int j2 = tt - 256; v = 0.25f * (bv[j2] + bv[j2+400] + bv[j2+800] + bv[j2+1200]); }
      bkv[tt] = v;
    }
  }
}

// ============ scores + softmax + top-k mask + rnn_in (-> gA cols 0..399) ============
__global__ __launch_bounds__(256) void score_kernel(
    const float* __restrict__ inputs, const u16* __restrict__ qlayb,
    const u16* __restrict__ kvb, const float* __restrict__ bk,
    const float* __restrict__ bkv,
    float* __restrict__ maskout, u16* __restrict__ gA)
{
  const int b = blockIdx.x;
  const int t = threadIdx.x;
  __shared__ float red[4][12];
  __shared__ float sprob[12];
  __shared__ float smask[6];

  const float k0v = b2f(kvb[(size_t)b * 768 + t]);
  const float bkv_ = bk[t];
  float part[12];
#pragma unroll
  for (int n = 0; n < 6; ++n) {
    const float q = b2f(qlayb[(size_t)b * 1536 + n * 256 + t]);
    part[2 * n]     = q * k0v;
    part[2 * n + 1] = q * bkv_;
  }
#pragma unroll
  for (int off = 32; off > 0; off >>= 1)
#pragma unroll
    for (int i = 0; i < 12; ++i)
      part[i] += __shfl_down(part[i], off);
  const int wave = t >> 6, lane = t & 63;
  if (lane == 0)
#pragma unroll
    for (int i = 0; i < 12; ++i) red[wave][i] = part[i];
  __syncthreads();
  if (t < 12) red[0][t] = (red[0][t] + red[1][t] + red[2][t] + red[3][t]) * (1.0f / 32.0f);
  __syncthreads();
  if (t < 6) {
    const float s0 = red[0][2 * t], s1 = red[0][2 * t + 1];
    const float mx = fmaxf(s0, s1);
    const float e0 = __expf(s0 - mx), e1 = __expf(s1 - mx);
    const float inv = 1.f / (e0 + e1);
    sprob[2 * t] = e0 * inv;
    sprob[2 * t + 1] = e1 * inv;
    const float* rd = inputs + (size_t)b * 518 + 512;
    const float mine = rd[t];
    int rank = 0;
#pragma unroll
    for (int j = 0; j < 6; ++j) {
      const float o = rd[j];
      rank += (o > mine) || (o == mine && j < t);
    }
    const float mk = (rank < 4) ? 1.f : 0.f;
    smask[t] = mk;
    maskout[(size_t)b * 6 + t] = mk;
  }
  __syncthreads();
  for (int c = t; c < 300; c += 256) {
    const int n = c / 50;
    const int v = (c % 50) * 8;
    const float p0 = sprob[2 * n], p1 = sprob[2 * n + 1], mk = smask[n];
    u16 st[8];
#pragma unroll
    for (int k = 0; k < 8; ++k)
      st[k] = f2b((p0 * b2f(kvb[(size_t)b * 768 + 256 + v + k]) + p1 * bkv[256 + v + k]) * mk);
    *reinterpret_cast<uint4*>(gA + (size_t)n * kGAs + (size_t)b * 1088 + v) =
        *reinterpret_cast<const uint4*>(st);
  }
}

// ============ comm attention ============
__global__ __launch_bounds__(256) void comm_kernel(
    const u16* __restrict__ cqv, u16* __restrict__ ctx)
{
  const int b = blockIdx.x, t = threadIdx.x;
  __shared__ float skc[768], sqc[768], svc[2400];
  __shared__ float spc[4][6][6];
  for (int i = t * 4; i < 4608; i += 1024) {
    const ushort4 u4 = *reinterpret_cast<const ushort4*>(cqv + (size_t)b * 4608 + i);
    const u16 uu[4] = {u4.x, u4.y, u4.z, u4.w};
#pragma unroll
    for (int j = 0; j < 4; ++j) {
      const int ii = i + j;
      const int m = ii / 768, c = ii % 768;
      const float v = b2f(uu[j]);
      if (c < 128) skc[m * 128 + c] = v;
      else if (c < 256) sqc[m * 128 + (c - 128)] = v;
      else if (c < 656) svc[m * 400 + (c - 256)] = v;
    }
  }
  __syncthreads();
  if (t < 144) {
    const int h = t / 36, n = (t % 36) / 6, m = t % 6;
    float s = 0.f;
#pragma unroll
    for (int d = 0; d < 32; ++d) s += sqc[n * 128 + h * 32 + d] * skc[m * 128 + h * 32 + d];
    spc[h][n][m] = s * 0.17677669529663687f;
  }
  __syncthreads();
  if (t < 24) {
    const int h = t / 6, n = t % 6;
    float mx = -3.0e38f;
#pragma unroll
    for (int m = 0; m < 6; ++m) mx = fmaxf(mx, spc[h][n][m]);
    float e[6], sum = 0.f;
#pragma unroll
    for (int m = 0; m < 6; ++m) { e[m] = __expf(spc[h][n][m] - mx); sum += e[m]; }
    const float inv = 1.f / sum;
#pragma unroll
    for (int m = 0; m < 6; ++m) spc[h][n][m] = e[m] * inv;
  }
  __syncthreads();
  for (int base = t * 4; base < 2400; base += 1024) {
    const int n = base / 400, rr = base % 400, h = rr / 100, v = rr % 100;
    ushort4 st;
    float s0 = 0.f, s1 = 0.f, s2 = 0.f, s3 = 0.f;
#pragma unroll
    for (int m = 0; m < 6; ++m) {
      const float p = spc[h][n][m];
      const float* vm = &svc[m * 400 + h * 100 + v];
      s0 += p * vm[0]; s1 += p * vm[1]; s2 += p * vm[2]; s3 += p * vm[3];
    }
    st.x = f2b(s0); st.y = f2b(s1); st.z = f2b(s2); st.w = f2b(s3);
    *reinterpret_cast<ushort4*>(ctx + (size_t)b * 2400 + base) = st;
  }
}

// ================= launch =================
extern "C" void kernel_launch(void* const* d_in, const int* in_sizes, int n_in,
                              void* d_out, int out_size, void* d_ws, size_t ws_size,
                              hipStream_t stream) {
  const float* inputs = (const float*)d_in[0];
  const float* hs     = (const float*)d_in[1];
  const float* cs     = (const float*)d_in[2];
  const float* Wk     = (const float*)d_in[3];
  const float* bk     = (const float*)d_in[4];
  const float* Wv     = (const float*)d_in[5];
  const float* bv     = (const float*)d_in[6];
  const float* Wq     = (const float*)d_in[7];
  const float* lstm_k = (const float*)d_in[8];
  const float* lstm_r = (const float*)d_in[9];
  const float* lstm_b = (const float*)d_in[10];
  const float* Wkc    = (const float*)d_in[11];
  const float* Wvc    = (const float*)d_in[12];
  const float* Wqc    = (const float*)d_in[13];
  const float* Wout   = (const float*)d_in[14];

  float* out = (float*)d_out;
  float* out_state = out;
  float* h_upd = out + kOS;
  float* c_upd = out + 2 * kOS;
  u16*   hnbf  = (u16*)d_out;     // scratch alias in out_state slot (stride kHnS rows)

  char* wsb = (char*)d_ws;
  u16* WkvT  = (u16*)(wsb + oWkvT);
  u16* WqT   = (u16*)(wsb + oWqT);
  u16* WcomT = (u16*)(wsb + oWcomT);
  u16* WoutT = (u16*)(wsb + oWoutT);
  u16* LstmT = (u16*)(wsb + oLstmT);
  float* bp    = (float*)(wsb + oBp);
  float* bkv   = (float*)(wsb + oBkv);
  float* maskf = (float*)(wsb + oMask);
  u16* gA    = (u16*)(wsb + oGA);
  u16* kvb   = (u16*)(wsb + oKV);
  u16* xbf   = (u16*)(wsb + oXbf);
  u16* qlayb = (u16*)(wsb + oQlay);
  u16* cqvb  = (u16*)(wsb + oCqv);
  u16* ctxb  = (u16*)(wsb + oCtx);

  dim3 B256(256);

  // ---- packs (2 launches) ----
  megapack_w<<<6132, B256, 0, stream>>>(Wk, Wv, Wkc, Wqc, Wvc, Wq, Wout, lstm_k, lstm_r,
                                        WkvT, WcomT, WqT, WoutT, LstmT);
  megapack_act<<<5180, B256, 0, stream>>>(inputs, hs, lstm_b, bk, bv, xbf, gA, bp, bkv, hnbf);

  // ---- kv = [x@Wk+bk | x@Wvavg+bvavg]  (N=656, K=512, nks=8; 192 tiles) ----
  gemm64<0><<<dim3(192), B256, 0, stream>>>(xbf, 512, 0, WkvT, 0, 512,
      kvb, 768, 0, bkv, 0, 656, 8, 1, 6,
      nullptr, nullptr, nullptr, nullptr);
  // ---- qlay (N=256/rim, K=640 w/ zero tail, nks=10; 384 tiles) ----
  gemm64<0><<<dim3(384), B256, 0, stream>>>(gA + 400, 1088, (long)kGAs, WqT, 256l*640, 640,
      qlayb, 1536, 256, nullptr, 0, 256, 10, 1, 2,
      nullptr, nullptr, nullptr, nullptr);

  score_kernel<<<4096, B256, 0, stream>>>(inputs, qlayb, kvb, bk, bkv, maskf, gA);

  // ---- gates (M=4096, N=2560 pad, K=1024) + fused LSTM; 256² 4-phase counted vmcnt ----
  gates256<<<dim3(960), dim3(512), 0, stream>>>(gA, LstmT, bp, cs, maskf, c_upd, h_upd, hnbf);

  // ---- comm projections fused: [kc|qc|vc] (N=656/rim, K=640 w/ zero tail, nks=10) ----
  gemm64<0><<<dim3(1152), B256, 0, stream>>>(hnbf, kHnS, 600, WcomT, 768l*640, 640,
      cqvb, 4608, 768, nullptr, 0, 656, 10, 1, 6,
      nullptr, nullptr, nullptr, nullptr);

  comm_kernel<<<4096, B256, 0, stream>>>(cqvb, ctxb);

  // ---- final: h_comm = ctx@Wout + h_new; masked select (N=600, K=448 w/ zero tail, nks=7) ----
  gemm64<1><<<dim3(960), B256, 0, stream>>>(ctxb, 2400, 400, WoutT, 640l*448, 448,
      nullptr, 0, 0, nullptr, 0, 600, 7, 0, 5,
      maskf, h_upd, hs, out_state);
}